// Round 6
// baseline (334.643 us; speedup 1.0000x reference)
//
#include <hip/hip_runtime.h>
#include <math.h>

#define BB 128
#define NN 256
#define EE 2048
#define BINS 16

typedef unsigned short u16;

// ---------------- CSR build, both sides: g in [0,2B) ----------------
__global__ void csr_kernel(const int* __restrict__ eq, const int* __restrict__ ec,
                           int* __restrict__ off, u16* __restrict__ srcs,
                           float* __restrict__ dvsg) {
    int g = blockIdx.x;                 // 0..2B-1
    int b = g < BB ? g : g - BB;
    const int* ei = g < BB ? eq : ec;
    int t = threadIdx.x;  // 256
    __shared__ int cnt[NN];
    __shared__ int sa[NN], sb[NN];
    __shared__ int cursor[NN];
    cnt[t] = 0;
    __syncthreads();
    const int* src = ei + b * 2 * EE;
    const int* dst = src + EE;
    for (int e = t; e < EE; e += 256) atomicAdd(&cnt[dst[e]], 1);
    __syncthreads();
    dvsg[g * NN + t] = rsqrtf((float)cnt[t] + 1.0f);   // deg^-1/2 (incl self-loop)
    sa[t] = cnt[t];
    __syncthreads();
    int* pin = sa; int* pout = sb;
    for (int d = 1; d < NN; d <<= 1) {
        int v = pin[t];
        if (t >= d) v += pin[t - d];
        pout[t] = v;
        __syncthreads();
        int* tmp = pin; pin = pout; pout = tmp;
    }
    int excl = pin[t] - cnt[t];
    off[g * 257 + t] = excl;
    if (t == 255) off[g * 257 + 256] = EE;
    cursor[t] = excl;
    __syncthreads();
    for (int e = t; e < EE; e += 256) {
        int d = dst[e], s = src[e];
        int pos = atomicAdd(&cursor[d], 1);
        srcs[g * EE + pos] = (u16)s;
    }
}

// ---------------- fused GCN layer: 512 thr, 4 rows x CPW cols per thread ----------------
// CHUNK=64: wave covers 8 cols (broadcast W) -> lane-varying LDS per FMA halves vs 4x4.
//   union LDS = hT two [256][33] panels = 67.6KB; total ~73.7KB -> 2 blocks/CU (16 waves).
// CHUNK=32: round-5 shape, union 33.8KB -> 4 blocks/CU.
// NSPLIT duplicates the (cheap, VALU-bound) GEMM and splits the gather by node range,
// purely to raise blocks/CU for layers whose natural grid is < 2/CU.
// NOTE: plain __launch_bounds__(512) — a min-waves clause forced VGPR=32 + spills (round 4).
template<int FIN, int FOUT, int CHUNK, bool RELU, int NSPLIT>
__global__ __launch_bounds__(512) void gcn_fused5(
        const float* __restrict__ X0, const float* __restrict__ X1,
        const float* __restrict__ W, const float* __restrict__ bias,
        const int* __restrict__ off, const u16* __restrict__ srcs,
        const float* __restrict__ dvsg, float* __restrict__ OUT) {
    constexpr int CHUNKS = FOUT / CHUNK;   // col chunks
    constexpr int CPW = CHUNK / 8;         // cols per wave (8 or 4)
    constexpr int NPANEL = CHUNK / 32;     // hT 32-col panels (2 or 1)
    constexpr int PSTR = NN * 33;          // panel stride (dwords), 8448 = 264*32 (bank-0 aligned)
    int blk = blockIdx.x;
    int g = blk % (2 * BB);
    int rest = blk / (2 * BB);
    int cb = (rest % CHUNKS) * CHUNK;
    int half = rest / CHUNKS;              // 0..NSPLIT-1
    int t = threadIdx.x;

    __shared__ float uni[PSTR * NPANEL];   // union: {xsT+wt} then hT panels
    __shared__ int   eoff[NN + 1];         // 1.0 KB
    __shared__ u16   esrc[EE];             // 4.0 KB
    __shared__ float dvs_s[NN];            // 1.0 KB
    float* xsT = uni;                      // [16][260] k-major, 4160 floats
    float* wt  = uni + 16 * 260;           // [16][CHUNK], ends at <=5184 < 8448
    float* hT  = uni;                      // [NPANEL][256][33] after the k-loop

    const float* xg = (g < BB) ? (X0 + (size_t)g * NN * FIN)
                               : (X1 + (size_t)(g - BB) * NN * FIN);
    const int* o = off + g * 257;
    const u16* sr = srcs + (size_t)g * EE;

    // stage edges + offsets + dvs (coalesced; overlaps k-loop prologue)
    for (int i = t; i < EE; i += 512) esrc[i] = sr[i];
    for (int i = t; i <= NN; i += 512) eoff[i] = o[i];
    if (t < NN) dvs_s[t] = dvsg[g * NN + t];

    int l = t & 63;        // lane -> node quad (rows 4l..4l+3)
    int wv = t >> 6;       // wave -> col group: cols CPW*wv .. CPW*wv+CPW-1

    float acc[4][CPW];
#pragma unroll
    for (int i = 0; i < 4; i++)
#pragma unroll
        for (int j = 0; j < CPW; j++) acc[i][j] = 0.f;

    // X staging: thread t stages 8 floats of row (t>>1) at k-offset (t&1)*8
    int sn = t >> 1, qk = (t & 1) * 8;
    const float* xr = xg + sn * FIN + qk;
    float4 v0 = *(const float4*)xr;
    float4 v1 = *(const float4*)(xr + 4);

    // W staging: EPT = CHUNK/32 floats per thread (2 for CHUNK=64, 1 for CHUNK=32)
    constexpr int EPT = CHUNK / 32;
    int wrow = t >> 5;                       // 16 rows, 32 threads each
    int wcol = (t & 31) * EPT;
    float wreg[EPT];
    if (EPT == 2) {
        float2 w2 = *(const float2*)&W[(size_t)wrow * FOUT + cb + wcol];
        wreg[0] = w2.x; wreg[1] = w2.y;
    } else {
        wreg[0] = W[(size_t)wrow * FOUT + cb + wcol];
    }

    for (int k0 = 0; k0 < FIN; k0 += 16) {
        xsT[(qk + 0) * 260 + sn] = v0.x;
        xsT[(qk + 1) * 260 + sn] = v0.y;
        xsT[(qk + 2) * 260 + sn] = v0.z;
        xsT[(qk + 3) * 260 + sn] = v0.w;
        xsT[(qk + 4) * 260 + sn] = v1.x;
        xsT[(qk + 5) * 260 + sn] = v1.y;
        xsT[(qk + 6) * 260 + sn] = v1.z;
        xsT[(qk + 7) * 260 + sn] = v1.w;
        if (EPT == 2) *(float2*)&wt[wrow * CHUNK + wcol] = make_float2(wreg[0], wreg[1]);
        else          wt[wrow * CHUNK + wcol] = wreg[0];
        __syncthreads();
        if (k0 + 16 < FIN) {
            xr += 16;
            v0 = *(const float4*)xr;
            v1 = *(const float4*)(xr + 4);
            if (EPT == 2) {
                float2 w2 = *(const float2*)&W[(size_t)(k0 + 16 + wrow) * FOUT + cb + wcol];
                wreg[0] = w2.x; wreg[1] = w2.y;
            } else {
                wreg[0] = W[(size_t)(k0 + 16 + wrow) * FOUT + cb + wcol];
            }
        }
#pragma unroll
        for (int k = 0; k < 16; k++) {
            float4 xv = *(const float4*)&xsT[k * 260 + 4 * l];   // lane-varying b128 (1KB/wave)
            float wc[CPW];                                        // wave-uniform broadcast (cheap)
#pragma unroll
            for (int j4 = 0; j4 < CPW; j4 += 4) {
                float4 w4 = *(const float4*)&wt[k * CHUNK + CPW * wv + j4];
                wc[j4] = w4.x; wc[j4 + 1] = w4.y; wc[j4 + 2] = w4.z; wc[j4 + 3] = w4.w;
            }
            float xq4[4] = {xv.x, xv.y, xv.z, xv.w};
#pragma unroll
            for (int i = 0; i < 4; i++)
#pragma unroll
                for (int j = 0; j < CPW; j++) acc[i][j] += xq4[i] * wc[j];
        }
        __syncthreads();   // last iteration: all xsT reads done -> hT may overwrite
    }
    {
        int colg = CPW * wv;
        int p = colg >> 5, cw = colg & 31;    // panel + col-within-panel
#pragma unroll
        for (int i = 0; i < 4; i++)
#pragma unroll
            for (int j4 = 0; j4 < CPW; j4 += 4)
                *(float4*)&hT[p * PSTR + (4 * l + i) * 33 + cw + j4] =
                    make_float4(acc[i][j4], acc[i][j4 + 1], acc[i][j4 + 2], acc[i][j4 + 3]);
    }
    __syncthreads();

    // CSR-gather: CHUNK channels per node; all lanes of a wave share one node's edges.
    constexpr int NG = 512 / CHUNK;          // node groups (8 or 16)
    int c = t & (CHUNK - 1), ng = t / CHUNK;
    int cp = c >> 5, cc = c & 31;
    float bb_ = bias[cb + c];
    float* outp = OUT + (size_t)g * NN * FOUT;
    constexpr int NSEG = NN / NSPLIT;
    int nlo = half * NSEG, nhi = nlo + NSEG;
    for (int n = nlo + ng; n < nhi; n += NG) {
        int j0 = eoff[n], j1 = eoff[n + 1];
        float dn = dvs_s[n];
        float a = 0.f;
        int j = j0;
        for (; j + 1 < j1; j += 2) {
            int s0 = esrc[j], s1 = esrc[j + 1];
            a += hT[cp * PSTR + s0 * 33 + cc] * (dvs_s[s0] * dn);
            a += hT[cp * PSTR + s1 * 33 + cc] * (dvs_s[s1] * dn);
        }
        if (j < j1) {
            int s0 = esrc[j];
            a += hT[cp * PSTR + s0 * 33 + cc] * (dvs_s[s0] * dn);
        }
        float d0i = 1.0f / ((float)(j1 - j0) + 1.0f);   // self-loop norm 1/deg
        float val = a + hT[cp * PSTR + n * 33 + cc] * d0i + bb_;
        if (RELU) val = fmaxf(val, 0.f);
        outp[n * FOUT + cb + c] = val;
    }
}

// ---------------- attention pooling (both sides): one block per graph ----------------
__global__ void attpool_kernel(const float* __restrict__ X, const float* __restrict__ Watt,
                               float* __restrict__ e) {
    int g = blockIdx.x;   // 0..2B-1
    int t = threadIdx.x;
    __shared__ float xs[NN * 33];
    __shared__ float red[256];
    __shared__ float mean_s[32], ctx_s[32], sc[NN];
    const float* x = X + (size_t)g * NN * 32;
    for (int i = t; i < NN * 32; i += 256) { int n = i >> 5, c = i & 31; xs[n * 33 + c] = x[i]; }
    __syncthreads();
    {
        int c = t & 31, p = t >> 5;
        float s = 0.f;
        for (int n = p * 32; n < (p + 1) * 32; n++) s += xs[n * 33 + c];
        red[t] = s;
    }
    __syncthreads();
    if (t < 32) {
        float m = 0.f;
        for (int p = 0; p < 8; p++) m += red[p * 32 + t];
        mean_s[t] = m / (float)NN;
    }
    __syncthreads();
    if (t < 32) {
        float a = 0.f;
        for (int f = 0; f < 32; f++) a += mean_s[f] * Watt[t * 32 + f];
        ctx_s[t] = tanhf(a);
    }
    __syncthreads();
    {
        float a = 0.f;
        for (int f = 0; f < 32; f++) a += xs[t * 33 + f] * ctx_s[f];
        sc[t] = 1.f / (1.f + expf(-a));
    }
    __syncthreads();
    {
        int c = t & 31, p = t >> 5;
        float s = 0.f;
        for (int n = p * 32; n < (p + 1) * 32; n++) s += xs[n * 33 + c] * sc[n];
        red[t] = s;
    }
    __syncthreads();
    if (t < 32) {
        float s = 0.f;
        for (int p = 0; p < 8; p++) s += red[p * 32 + t];
        e[g * 32 + t] = s;
    }
}

// ---------------- pairwise dots: 128x128 tile, 8x8 per thread, f-major LDS ----------------
#define PD_STAGE_AND_DOT \
    int blk = blockIdx.x; \
    int b = blk >> 2; \
    int tq = (blk >> 1) & 1, tc = blk & 1; \
    __shared__ float qsT[32 * 132]; \
    __shared__ float csT[32 * 132]; \
    int t = threadIdx.x; \
    { \
        int n = t >> 1, f0 = (t & 1) * 16; \
        const float* qp = Q + ((size_t)b * NN + tq * 128 + n) * 32 + f0; \
        const float* cp = C + ((size_t)b * NN + tc * 128 + n) * 32 + f0; \
        float qa16[16], ca16[16]; \
        *(float4*)&qa16[0]  = *(const float4*)(qp); \
        *(float4*)&qa16[4]  = *(const float4*)(qp + 4); \
        *(float4*)&qa16[8]  = *(const float4*)(qp + 8); \
        *(float4*)&qa16[12] = *(const float4*)(qp + 12); \
        *(float4*)&ca16[0]  = *(const float4*)(cp); \
        *(float4*)&ca16[4]  = *(const float4*)(cp + 4); \
        *(float4*)&ca16[8]  = *(const float4*)(cp + 8); \
        *(float4*)&ca16[12] = *(const float4*)(cp + 12); \
        _Pragma("unroll") \
        for (int m = 0; m < 16; m++) { \
            qsT[(f0 + m) * 132 + n] = qa16[m]; \
            csT[(f0 + m) * 132 + n] = ca16[m]; \
        } \
    } \
    __syncthreads(); \
    int rg = (t >> 4) * 4, cg = (t & 15) * 4; \
    float acc[8][8]; \
    _Pragma("unroll") \
    for (int i = 0; i < 8; i++) \
        _Pragma("unroll") \
        for (int j = 0; j < 8; j++) acc[i][j] = 0.f; \
    _Pragma("unroll 2") \
    for (int f = 0; f < 32; f++) { \
        float4 qa = *(const float4*)&qsT[f * 132 + rg]; \
        float4 qb = *(const float4*)&qsT[f * 132 + 64 + rg]; \
        float4 ca = *(const float4*)&csT[f * 132 + cg]; \
        float4 cb = *(const float4*)&csT[f * 132 + 64 + cg]; \
        float qv[8] = {qa.x, qa.y, qa.z, qa.w, qb.x, qb.y, qb.z, qb.w}; \
        float cv[8] = {ca.x, ca.y, ca.z, ca.w, cb.x, cb.y, cb.z, cb.w}; \
        _Pragma("unroll") \
        for (int i = 0; i < 8; i++) \
            _Pragma("unroll") \
            for (int j = 0; j < 8; j++) acc[i][j] += qv[i] * cv[j]; \
    }

__global__ __launch_bounds__(256, 4) void pairdot_minmax(
        const float* __restrict__ Q, const float* __restrict__ C,
        float* __restrict__ bmin, float* __restrict__ bmax) {
    PD_STAGE_AND_DOT
    float lmin = acc[0][0], lmax = acc[0][0];
#pragma unroll
    for (int i = 0; i < 8; i++)
#pragma unroll
        for (int j = 0; j < 8; j++) {
            lmin = fminf(lmin, acc[i][j]);
            lmax = fmaxf(lmax, acc[i][j]);
        }
    __shared__ float rmin[256], rmax[256];
    rmin[t] = lmin; rmax[t] = lmax;
    __syncthreads();
    for (int s = 128; s > 0; s >>= 1) {
        if (t < s) { rmin[t] = fminf(rmin[t], rmin[t + s]); rmax[t] = fmaxf(rmax[t], rmax[t + s]); }
        __syncthreads();
    }
    if (t == 0) { bmin[blk] = rmin[0]; bmax[blk] = rmax[0]; }
}

// ---------------- global min/max reduce (1 block) + zero counts ----------------
__global__ void minmax_kernel(const float* __restrict__ bmin, const float* __restrict__ bmax,
                              float* __restrict__ lohi, float* __restrict__ counts) {
    __shared__ float rmin[256], rmax[256];
    int t = threadIdx.x;
    float lmin = 1e30f, lmax = -1e30f;
    for (int i = t; i < 512; i += 256) { lmin = fminf(lmin, bmin[i]); lmax = fmaxf(lmax, bmax[i]); }
    rmin[t] = lmin; rmax[t] = lmax;
    __syncthreads();
    for (int s = 128; s > 0; s >>= 1) {
        if (t < s) { rmin[t] = fminf(rmin[t], rmin[t + s]); rmax[t] = fmaxf(rmax[t], rmax[t + s]); }
        __syncthreads();
    }
    if (t == 0) { lohi[0] = rmin[0]; lohi[1] = rmax[0]; }
    if (t < BINS) counts[t] = 0.f;
}

// ---------------- pass 2: recompute dots, bit-sliced ballot histogram ----------------
__global__ __launch_bounds__(256, 4) void pairdot_hist(
        const float* __restrict__ Q, const float* __restrict__ C,
        const float* __restrict__ lohi, float* __restrict__ counts) {
    PD_STAGE_AND_DOT
    float lo = lohi[0], hi = lohi[1];
    float scale = (float)BINS / (hi - lo);
    int lane = t & 63;
    int cnt = 0;   // lane L accumulates count for bin (L & 15)
#pragma unroll
    for (int i = 0; i < 8; i++)
#pragma unroll
        for (int j = 0; j < 8; j++) {
            int idx = (int)floorf((acc[i][j] - lo) * scale);
            idx = min(max(idx, 0), BINS - 1);
            unsigned long long b0 = __ballot((idx & 1) != 0);
            unsigned long long b1 = __ballot((idx & 2) != 0);
            unsigned long long b2 = __ballot((idx & 4) != 0);
            unsigned long long b3 = __ballot((idx & 8) != 0);
            unsigned long long msk = ((lane & 1) ? b0 : ~b0);
            msk &= ((lane & 2) ? b1 : ~b1);
            msk &= ((lane & 4) ? b2 : ~b2);
            msk &= ((lane & 8) ? b3 : ~b3);
            cnt += __popcll(msk);
        }
    __shared__ float wbins[4][BINS];
    int wave = t >> 6;
    if (lane < BINS) wbins[wave][lane] = (float)cnt;
    __syncthreads();
    if (t < BINS) {
        atomicAdd(&counts[t], wbins[0][t] + wbins[1][t] + wbins[2][t] + wbins[3][t]);
    }
}

// ---------------- NTN + histogram concat + fc1 + fc2 head ----------------
__global__ void final_kernel(const float* __restrict__ e1, const float* __restrict__ e2,
                             const float* __restrict__ ntnW, const float* __restrict__ ntnV,
                             const float* __restrict__ ntnb, const float* __restrict__ counts,
                             const float* __restrict__ fc1W, const float* __restrict__ fc1b,
                             const float* __restrict__ fc2W, const float* __restrict__ fc2b,
                             float* __restrict__ out) {
    int b = blockIdx.x;
    int t = threadIdx.x;
    __shared__ float a1[32], a2[32], red[256], z[32], u[16];
    if (t < 32) a1[t] = e1[b * 32 + t];
    else if (t < 64) a2[t - 32] = e2[b * 32 + t - 32];
    __syncthreads();
    int tt = t >> 4, g = t & 15;
    float p = 0.f;
#pragma unroll
    for (int ii = 0; ii < 2; ii++) {
        int i = g + 16 * ii;
        float d = 0.f;
        const float* wr = ntnW + (tt * 32 + i) * 32;
        for (int j = 0; j < 32; j++) d += wr[j] * a2[j];
        p += a1[i] * d;
    }
    red[t] = p;
    __syncthreads();
    if (t < 16) {
        float s = 0.f;
        for (int g2 = 0; g2 < 16; g2++) s += red[t * 16 + g2];
        float lin = ntnb[t];
        for (int i = 0; i < 32; i++) lin += ntnV[t * 64 + i] * a1[i];
        for (int i = 0; i < 32; i++) lin += ntnV[t * 64 + 32 + i] * a2[i];
        z[t] = fmaxf(s + lin, 0.f);
    } else if (t < 32) {
        float tot = 0.f;
        for (int i = 0; i < BINS; i++) tot += counts[i];
        z[t] = counts[t - 16] / tot;
    }
    __syncthreads();
    if (t < 16) {
        float a = fc1b[t];
        for (int i = 0; i < 32; i++) a += fc1W[t * 32 + i] * z[i];
        u[t] = fmaxf(a, 0.f);
    }
    __syncthreads();
    if (t == 0) {
        float a = fc2b[0];
        for (int i = 0; i < 16; i++) a += fc2W[i] * u[i];
        out[b] = 1.f / (1.f + expf(-a));
    }
}

extern "C" void kernel_launch(void* const* d_in, const int* in_sizes, int n_in,
                              void* d_out, int out_size, void* d_ws, size_t ws_size,
                              hipStream_t stream) {
    const float* xq   = (const float*)d_in[0];
    const float* xc   = (const float*)d_in[1];
    const int*   eq   = (const int*)d_in[2];
    const int*   ec   = (const int*)d_in[3];
    const float* W1   = (const float*)d_in[4];
    const float* b1   = (const float*)d_in[5];
    const float* W2   = (const float*)d_in[6];
    const float* b2   = (const float*)d_in[7];
    const float* W3   = (const float*)d_in[8];
    const float* b3   = (const float*)d_in[9];
    const float* Watt = (const float*)d_in[10];
    const float* ntnW = (const float*)d_in[11];
    const float* ntnV = (const float*)d_in[12];
    const float* ntnb = (const float*)d_in[13];
    const float* fc1W = (const float*)d_in[14];
    const float* fc1b = (const float*)d_in[15];
    const float* fc2W = (const float*)d_in[16];
    const float* fc2b = (const float*)d_in[17];
    float* out = (float*)d_out;
    float* ws  = (float*)d_ws;

    // ---- workspace layout (float indices), [2B] contiguous buffers ----
    float* O3   = ws;                            // 2*B*N*32  = 2097152
    float* e12  = O3 + 2097152;                  // 8192
    float* bmin = e12 + 8192;                    // 2048 (512 used)
    float* bmax = bmin + 2048;                   // 2048 (512 used)
    float* lohi = bmax + 2048;                   // 2
    float* cntw = lohi + 2;                      // 16
    int*   off  = (int*)(ws + 2109504);          // 2B*257 = 65792 ints
    u16*   srcs = (u16*)(off + 65792);           // 2B*E u16 = 262144 floats
    float* dvsg = ws + 2437440;                  // 2B*256 = 65536
    float* O1   = ws + 3223872;                  // 2*B*N*128 = 8388608
    float* O2   = O1 + 8388608;                  // 2*B*N*64  = 4194304

    float* O3Q = O3;
    float* O3C = O3 + (size_t)BB * NN * 32;
    float* e1w = e12;
    float* e2w = e12 + BB * 32;

    csr_kernel<<<2 * BB, 256, 0, stream>>>(eq, ec, off, srcs, dvsg);

    // L1: 2 chunks of 64 cols -> 512 blocks (2/CU)
    gcn_fused5<128, 128, 64, true, 1><<<2 * 2 * BB, 512, 0, stream>>>(
        xq, xc, W1, b1, off, srcs, dvsg, O1);
    // L2: 1 chunk of 64 cols, NSPLIT=2 -> 512 blocks (2/CU)
    gcn_fused5<128, 64, 64, true, 2><<<2 * 2 * BB, 512, 0, stream>>>(
        O1, O1 + (size_t)BB * NN * 128, W2, b2, off, srcs, dvsg, O2);
    // L3: 1 chunk of 32 cols, NSPLIT=4 -> 1024 blocks (4/CU)
    gcn_fused5<64, 32, 32, false, 4><<<4 * 2 * BB, 512, 0, stream>>>(
        O2, O2 + (size_t)BB * NN * 64, W3, b3, off, srcs, dvsg, O3);

    attpool_kernel<<<2 * BB, 256, 0, stream>>>(O3, Watt, e12);

    pairdot_minmax<<<BB * 4, 256, 0, stream>>>(O3Q, O3C, bmin, bmax);
    minmax_kernel<<<1, 256, 0, stream>>>(bmin, bmax, lohi, cntw);
    pairdot_hist<<<BB * 4, 256, 0, stream>>>(O3Q, O3C, lohi, cntw);

    final_kernel<<<BB, 256, 0, stream>>>(e1w, e2w, ntnW, ntnV, ntnb, cntw,
                                         fc1W, fc1b, fc2W, fc2b, out);
}

// Round 7
// 299.609 us; speedup vs baseline: 1.1169x; 1.1169x over previous
//
#include <hip/hip_runtime.h>
#include <math.h>

#define BB 128
#define NN 256
#define EE 2048
#define BINS 16

typedef unsigned short u16;

// ---------------- CSR build, both sides: g in [0,2B) ----------------
__global__ void csr_kernel(const int* __restrict__ eq, const int* __restrict__ ec,
                           int* __restrict__ off, u16* __restrict__ srcs,
                           float* __restrict__ wts) {
    int g = blockIdx.x;                 // 0..2B-1
    int b = g < BB ? g : g - BB;
    const int* ei = g < BB ? eq : ec;
    int t = threadIdx.x;  // 256
    __shared__ int cnt[NN];
    __shared__ int sa[NN], sb[NN];
    __shared__ int cursor[NN];
    __shared__ float dvs[NN];
    cnt[t] = 0;
    __syncthreads();
    const int* src = ei + b * 2 * EE;
    const int* dst = src + EE;
    for (int e = t; e < EE; e += 256) atomicAdd(&cnt[dst[e]], 1);
    __syncthreads();
    dvs[t] = rsqrtf((float)cnt[t] + 1.0f);   // deg^-1/2 (incl self-loop)
    sa[t] = cnt[t];
    __syncthreads();
    int* pin = sa; int* pout = sb;
    for (int d = 1; d < NN; d <<= 1) {
        int v = pin[t];
        if (t >= d) v += pin[t - d];
        pout[t] = v;
        __syncthreads();
        int* tmp = pin; pin = pout; pout = tmp;
    }
    int excl = pin[t] - cnt[t];
    off[g * 257 + t] = excl;
    if (t == 255) off[g * 257 + 256] = EE;
    cursor[t] = excl;
    __syncthreads();
    for (int e = t; e < EE; e += 256) {
        int d = dst[e], s = src[e];
        int pos = atomicAdd(&cursor[d], 1);
        srcs[g * EE + pos] = (u16)s;
        wts[g * EE + pos] = dvs[s] * dvs[d];
    }
}

// ---------------- fused GCN layer: R0 4x4 FMA body + dbuf staging + depth-2 prefetch ----
// 512 thr, per-thread 4 rows x 4 cols, k-tile 16, ONE barrier per k-tile.
// union uni[9344]: two {xsT[16*260] + wt[16*32]} buffers (4672 each); hT[256*33]=8448
// overlays both after the k-loop (final barrier separates last reads from hT writes).
// LDS ~50.7KB -> 3 blocks/CU. Plain __launch_bounds__(512): a min-waves clause forced
// VGPR=32 + massive scratch spills in round 4.
template<int FIN, int FOUT, bool RELU, int NSPLIT>
__global__ __launch_bounds__(512) void gcn_fused6(
        const float* __restrict__ X0, const float* __restrict__ X1,
        const float* __restrict__ W, const float* __restrict__ bias,
        const int* __restrict__ off, const u16* __restrict__ srcs,
        const float* __restrict__ wts, float* __restrict__ OUT) {
    constexpr int CHUNKS = FOUT / 32;
    constexpr int NW = FIN / 16;           // k-windows (8 or 4)
    constexpr int BUF = 16 * 260 + 16 * 32; // 4672 floats per staging buffer
    int blk = blockIdx.x;
    int g = blk % (2 * BB);
    int rest = blk / (2 * BB);
    int cb = (rest % CHUNKS) * 32;
    int half = rest / CHUNKS;              // 0..NSPLIT-1
    int t = threadIdx.x;

    __shared__ float uni[2 * BUF];         // 37.4 KB union (staging dbuf / hT)
    __shared__ int   eoff[NN + 1];         // 1.0 KB
    __shared__ u16   esrc[EE];             // 4.0 KB
    __shared__ float ewt[EE];              // 8.0 KB
    float* hT = uni;                       // [256][33] after the k-loop

    const float* xg = (g < BB) ? (X0 + (size_t)g * NN * FIN)
                               : (X1 + (size_t)(g - BB) * NN * FIN);
    const int* o = off + g * 257;
    const u16* sr = srcs + (size_t)g * EE;
    const float* wg = wts + (size_t)g * EE;

    // stage edges + offsets (coalesced; overlaps k-loop prologue)
    for (int i = t; i < EE; i += 512) { esrc[i] = sr[i]; ewt[i] = wg[i]; }
    for (int i = t; i <= NN; i += 512) eoff[i] = o[i];

    int l = t & 63;        // lane -> node quad (rows 4l..4l+3)
    int wv = t >> 6;       // wave -> channel quad (cols 4wv..4wv+3)

    float acc[4][4];
#pragma unroll
    for (int i = 0; i < 4; i++)
#pragma unroll
        for (int j = 0; j < 4; j++) acc[i][j] = 0.f;

    int sn = t >> 1, qk = (t & 1) * 8;
    const float* xr = xg + sn * FIN + qk;
    int wrow = t >> 5, wcol = t & 31;

    auto stage = [&](float* buf, const float4& s0, const float4& s1, float sw) {
        buf[(qk + 0) * 260 + sn] = s0.x;
        buf[(qk + 1) * 260 + sn] = s0.y;
        buf[(qk + 2) * 260 + sn] = s0.z;
        buf[(qk + 3) * 260 + sn] = s0.w;
        buf[(qk + 4) * 260 + sn] = s1.x;
        buf[(qk + 5) * 260 + sn] = s1.y;
        buf[(qk + 6) * 260 + sn] = s1.z;
        buf[(qk + 7) * 260 + sn] = s1.w;
        buf[16 * 260 + t] = sw;            // wt[t]
    };

    // prologue: window0 -> regs A, window1 -> regs B; stage w0 into buf0; issue w2 -> A
    float4 rA0 = *(const float4*)(xr);
    float4 rA1 = *(const float4*)(xr + 4);
    float  wA  = W[(size_t)wrow * FOUT + cb + wcol];
    float4 rB0 = *(const float4*)(xr + 16);
    float4 rB1 = *(const float4*)(xr + 20);
    float  wB  = W[(size_t)(16 + wrow) * FOUT + cb + wcol];
    stage(uni, rA0, rA1, wA);
    if (NW > 2) {
        rA0 = *(const float4*)(xr + 32);
        rA1 = *(const float4*)(xr + 36);
        wA  = W[(size_t)(32 + wrow) * FOUT + cb + wcol];
    }
    __syncthreads();

#pragma unroll
    for (int it = 0; it < NW; ++it) {
        float* cur = uni + (it & 1) * BUF;
        if (it + 1 < NW) {
            float* nb = uni + ((it + 1) & 1) * BUF;
            if (((it + 1) & 1) == 0) stage(nb, rA0, rA1, wA);
            else                     stage(nb, rB0, rB1, wB);
            if (it + 3 < NW) {
                int ko = (it + 3) * 16;
                if (((it + 3) & 1) == 0) {
                    rA0 = *(const float4*)(xr + ko);
                    rA1 = *(const float4*)(xr + ko + 4);
                    wA  = W[(size_t)(ko + wrow) * FOUT + cb + wcol];
                } else {
                    rB0 = *(const float4*)(xr + ko);
                    rB1 = *(const float4*)(xr + ko + 4);
                    wB  = W[(size_t)(ko + wrow) * FOUT + cb + wcol];
                }
            }
        }
#pragma unroll
        for (int k = 0; k < 16; k++) {
            float4 xv  = *(const float4*)&cur[k * 260 + 4 * l];          // lane-varying b128
            float4 wvv = *(const float4*)&cur[16 * 260 + k * 32 + 4 * wv]; // wave-uniform broadcast
            acc[0][0] += xv.x * wvv.x; acc[0][1] += xv.x * wvv.y;
            acc[0][2] += xv.x * wvv.z; acc[0][3] += xv.x * wvv.w;
            acc[1][0] += xv.y * wvv.x; acc[1][1] += xv.y * wvv.y;
            acc[1][2] += xv.y * wvv.z; acc[1][3] += xv.y * wvv.w;
            acc[2][0] += xv.z * wvv.x; acc[2][1] += xv.z * wvv.y;
            acc[2][2] += xv.z * wvv.z; acc[2][3] += xv.z * wvv.w;
            acc[3][0] += xv.w * wvv.x; acc[3][1] += xv.w * wvv.y;
            acc[3][2] += xv.w * wvv.z; acc[3][3] += xv.w * wvv.w;
        }
        __syncthreads();   // one barrier per k-tile; final one guards hT overlay
    }
#pragma unroll
    for (int i = 0; i < 4; i++)
#pragma unroll
        for (int j = 0; j < 4; j++)
            hT[(4 * l + i) * 33 + 4 * wv + j] = acc[i][j];
    __syncthreads();

    // CSR-gather aggregation: everything in LDS (precomputed edge weights)
    int c = t & 31, ng = t >> 5;
    float bb_ = bias[cb + c];
    float* outp = OUT + (size_t)g * NN * FOUT;
    constexpr int NSEG = NN / NSPLIT;
    int nlo = half * NSEG, nhi = nlo + NSEG;
    for (int n = nlo + ng; n < nhi; n += 16) {
        int j0 = eoff[n], j1 = eoff[n + 1];
        float a = 0.f;
        int j = j0;
        for (; j + 1 < j1; j += 2) {
            int s0 = esrc[j], s1 = esrc[j + 1];
            a += hT[s0 * 33 + c] * ewt[j];
            a += hT[s1 * 33 + c] * ewt[j + 1];
        }
        if (j < j1) {
            a += hT[esrc[j] * 33 + c] * ewt[j];
        }
        float d0i = 1.0f / ((float)(j1 - j0) + 1.0f);   // self-loop norm 1/deg
        float val = a + hT[n * 33 + c] * d0i + bb_;
        if (RELU) val = fmaxf(val, 0.f);
        outp[n * FOUT + cb + c] = val;
    }
}

// ---------------- attention pooling (both sides): one block per graph ----------------
__global__ void attpool_kernel(const float* __restrict__ X, const float* __restrict__ Watt,
                               float* __restrict__ e) {
    int g = blockIdx.x;   // 0..2B-1
    int t = threadIdx.x;
    __shared__ float xs[NN * 33];
    __shared__ float red[256];
    __shared__ float mean_s[32], ctx_s[32], sc[NN];
    const float* x = X + (size_t)g * NN * 32;
    for (int i = t; i < NN * 32; i += 256) { int n = i >> 5, c = i & 31; xs[n * 33 + c] = x[i]; }
    __syncthreads();
    {
        int c = t & 31, p = t >> 5;
        float s = 0.f;
        for (int n = p * 32; n < (p + 1) * 32; n++) s += xs[n * 33 + c];
        red[t] = s;
    }
    __syncthreads();
    if (t < 32) {
        float m = 0.f;
        for (int p = 0; p < 8; p++) m += red[p * 32 + t];
        mean_s[t] = m / (float)NN;
    }
    __syncthreads();
    if (t < 32) {
        float a = 0.f;
        for (int f = 0; f < 32; f++) a += mean_s[f] * Watt[t * 32 + f];
        ctx_s[t] = tanhf(a);
    }
    __syncthreads();
    {
        float a = 0.f;
        for (int f = 0; f < 32; f++) a += xs[t * 33 + f] * ctx_s[f];
        sc[t] = 1.f / (1.f + expf(-a));
    }
    __syncthreads();
    {
        int c = t & 31, p = t >> 5;
        float s = 0.f;
        for (int n = p * 32; n < (p + 1) * 32; n++) s += xs[n * 33 + c] * sc[n];
        red[t] = s;
    }
    __syncthreads();
    if (t < 32) {
        float s = 0.f;
        for (int p = 0; p < 8; p++) s += red[p * 32 + t];
        e[g * 32 + t] = s;
    }
}

// ---------------- pairwise dots: 128x128 tile, 8x8 per thread, f-major LDS ----------------
#define PD_STAGE_AND_DOT \
    int blk = blockIdx.x; \
    int b = blk >> 2; \
    int tq = (blk >> 1) & 1, tc = blk & 1; \
    __shared__ float qsT[32 * 132]; \
    __shared__ float csT[32 * 132]; \
    int t = threadIdx.x; \
    { \
        int n = t >> 1, f0 = (t & 1) * 16; \
        const float* qp = Q + ((size_t)b * NN + tq * 128 + n) * 32 + f0; \
        const float* cp = C + ((size_t)b * NN + tc * 128 + n) * 32 + f0; \
        float qa16[16], ca16[16]; \
        *(float4*)&qa16[0]  = *(const float4*)(qp); \
        *(float4*)&qa16[4]  = *(const float4*)(qp + 4); \
        *(float4*)&qa16[8]  = *(const float4*)(qp + 8); \
        *(float4*)&qa16[12] = *(const float4*)(qp + 12); \
        *(float4*)&ca16[0]  = *(const float4*)(cp); \
        *(float4*)&ca16[4]  = *(const float4*)(cp + 4); \
        *(float4*)&ca16[8]  = *(const float4*)(cp + 8); \
        *(float4*)&ca16[12] = *(const float4*)(cp + 12); \
        _Pragma("unroll") \
        for (int m = 0; m < 16; m++) { \
            qsT[(f0 + m) * 132 + n] = qa16[m]; \
            csT[(f0 + m) * 132 + n] = ca16[m]; \
        } \
    } \
    __syncthreads(); \
    int rg = (t >> 4) * 4, cg = (t & 15) * 4; \
    float acc[8][8]; \
    _Pragma("unroll") \
    for (int i = 0; i < 8; i++) \
        _Pragma("unroll") \
        for (int j = 0; j < 8; j++) acc[i][j] = 0.f; \
    _Pragma("unroll 2") \
    for (int f = 0; f < 32; f++) { \
        float4 qa = *(const float4*)&qsT[f * 132 + rg]; \
        float4 qb = *(const float4*)&qsT[f * 132 + 64 + rg]; \
        float4 ca = *(const float4*)&csT[f * 132 + cg]; \
        float4 cb = *(const float4*)&csT[f * 132 + 64 + cg]; \
        float qv[8] = {qa.x, qa.y, qa.z, qa.w, qb.x, qb.y, qb.z, qb.w}; \
        float cv[8] = {ca.x, ca.y, ca.z, ca.w, cb.x, cb.y, cb.z, cb.w}; \
        _Pragma("unroll") \
        for (int i = 0; i < 8; i++) \
            _Pragma("unroll") \
            for (int j = 0; j < 8; j++) acc[i][j] += qv[i] * cv[j]; \
    }

__global__ __launch_bounds__(256, 4) void pairdot_minmax(
        const float* __restrict__ Q, const float* __restrict__ C,
        float* __restrict__ bmin, float* __restrict__ bmax) {
    PD_STAGE_AND_DOT
    float lmin = acc[0][0], lmax = acc[0][0];
#pragma unroll
    for (int i = 0; i < 8; i++)
#pragma unroll
        for (int j = 0; j < 8; j++) {
            lmin = fminf(lmin, acc[i][j]);
            lmax = fmaxf(lmax, acc[i][j]);
        }
    __shared__ float rmin[256], rmax[256];
    rmin[t] = lmin; rmax[t] = lmax;
    __syncthreads();
    for (int s = 128; s > 0; s >>= 1) {
        if (t < s) { rmin[t] = fminf(rmin[t], rmin[t + s]); rmax[t] = fmaxf(rmax[t], rmax[t + s]); }
        __syncthreads();
    }
    if (t == 0) { bmin[blk] = rmin[0]; bmax[blk] = rmax[0]; }
}

// ---------------- global min/max reduce (1 block) + zero counts ----------------
__global__ void minmax_kernel(const float* __restrict__ bmin, const float* __restrict__ bmax,
                              float* __restrict__ lohi, float* __restrict__ counts) {
    __shared__ float rmin[256], rmax[256];
    int t = threadIdx.x;
    float lmin = 1e30f, lmax = -1e30f;
    for (int i = t; i < 512; i += 256) { lmin = fminf(lmin, bmin[i]); lmax = fmaxf(lmax, bmax[i]); }
    rmin[t] = lmin; rmax[t] = lmax;
    __syncthreads();
    for (int s = 128; s > 0; s >>= 1) {
        if (t < s) { rmin[t] = fminf(rmin[t], rmin[t + s]); rmax[t] = fmaxf(rmax[t], rmax[t + s]); }
        __syncthreads();
    }
    if (t == 0) { lohi[0] = rmin[0]; lohi[1] = rmax[0]; }
    if (t < BINS) counts[t] = 0.f;
}

// ---------------- pass 2: recompute dots, bit-sliced ballot histogram ----------------
__global__ __launch_bounds__(256, 4) void pairdot_hist(
        const float* __restrict__ Q, const float* __restrict__ C,
        const float* __restrict__ lohi, float* __restrict__ counts) {
    PD_STAGE_AND_DOT
    float lo = lohi[0], hi = lohi[1];
    float scale = (float)BINS / (hi - lo);
    int lane = t & 63;
    int cnt = 0;   // lane L accumulates count for bin (L & 15)
#pragma unroll
    for (int i = 0; i < 8; i++)
#pragma unroll
        for (int j = 0; j < 8; j++) {
            int idx = (int)floorf((acc[i][j] - lo) * scale);
            idx = min(max(idx, 0), BINS - 1);
            unsigned long long b0 = __ballot((idx & 1) != 0);
            unsigned long long b1 = __ballot((idx & 2) != 0);
            unsigned long long b2 = __ballot((idx & 4) != 0);
            unsigned long long b3 = __ballot((idx & 8) != 0);
            unsigned long long msk = ((lane & 1) ? b0 : ~b0);
            msk &= ((lane & 2) ? b1 : ~b1);
            msk &= ((lane & 4) ? b2 : ~b2);
            msk &= ((lane & 8) ? b3 : ~b3);
            cnt += __popcll(msk);
        }
    __shared__ float wbins[4][BINS];
    int wave = t >> 6;
    if (lane < BINS) wbins[wave][lane] = (float)cnt;
    __syncthreads();
    if (t < BINS) {
        atomicAdd(&counts[t], wbins[0][t] + wbins[1][t] + wbins[2][t] + wbins[3][t]);
    }
}

// ---------------- NTN + histogram concat + fc1 + fc2 head ----------------
__global__ void final_kernel(const float* __restrict__ e1, const float* __restrict__ e2,
                             const float* __restrict__ ntnW, const float* __restrict__ ntnV,
                             const float* __restrict__ ntnb, const float* __restrict__ counts,
                             const float* __restrict__ fc1W, const float* __restrict__ fc1b,
                             const float* __restrict__ fc2W, const float* __restrict__ fc2b,
                             float* __restrict__ out) {
    int b = blockIdx.x;
    int t = threadIdx.x;
    __shared__ float a1[32], a2[32], red[256], z[32], u[16];
    if (t < 32) a1[t] = e1[b * 32 + t];
    else if (t < 64) a2[t - 32] = e2[b * 32 + t - 32];
    __syncthreads();
    int tt = t >> 4, g = t & 15;
    float p = 0.f;
#pragma unroll
    for (int ii = 0; ii < 2; ii++) {
        int i = g + 16 * ii;
        float d = 0.f;
        const float* wr = ntnW + (tt * 32 + i) * 32;
        for (int j = 0; j < 32; j++) d += wr[j] * a2[j];
        p += a1[i] * d;
    }
    red[t] = p;
    __syncthreads();
    if (t < 16) {
        float s = 0.f;
        for (int g2 = 0; g2 < 16; g2++) s += red[t * 16 + g2];
        float lin = ntnb[t];
        for (int i = 0; i < 32; i++) lin += ntnV[t * 64 + i] * a1[i];
        for (int i = 0; i < 32; i++) lin += ntnV[t * 64 + 32 + i] * a2[i];
        z[t] = fmaxf(s + lin, 0.f);
    } else if (t < 32) {
        float tot = 0.f;
        for (int i = 0; i < BINS; i++) tot += counts[i];
        z[t] = counts[t - 16] / tot;
    }
    __syncthreads();
    if (t < 16) {
        float a = fc1b[t];
        for (int i = 0; i < 32; i++) a += fc1W[t * 32 + i] * z[i];
        u[t] = fmaxf(a, 0.f);
    }
    __syncthreads();
    if (t == 0) {
        float a = fc2b[0];
        for (int i = 0; i < 16; i++) a += fc2W[i] * u[i];
        out[b] = 1.f / (1.f + expf(-a));
    }
}

extern "C" void kernel_launch(void* const* d_in, const int* in_sizes, int n_in,
                              void* d_out, int out_size, void* d_ws, size_t ws_size,
                              hipStream_t stream) {
    const float* xq   = (const float*)d_in[0];
    const float* xc   = (const float*)d_in[1];
    const int*   eq   = (const int*)d_in[2];
    const int*   ec   = (const int*)d_in[3];
    const float* W1   = (const float*)d_in[4];
    const float* b1   = (const float*)d_in[5];
    const float* W2   = (const float*)d_in[6];
    const float* b2   = (const float*)d_in[7];
    const float* W3   = (const float*)d_in[8];
    const float* b3   = (const float*)d_in[9];
    const float* Watt = (const float*)d_in[10];
    const float* ntnW = (const float*)d_in[11];
    const float* ntnV = (const float*)d_in[12];
    const float* ntnb = (const float*)d_in[13];
    const float* fc1W = (const float*)d_in[14];
    const float* fc1b = (const float*)d_in[15];
    const float* fc2W = (const float*)d_in[16];
    const float* fc2b = (const float*)d_in[17];
    float* out = (float*)d_out;
    float* ws  = (float*)d_ws;

    // ---- workspace layout (float indices), [2B] contiguous buffers ----
    float* O3   = ws;                            // 2*B*N*32  = 2097152
    float* e12  = O3 + 2097152;                  // 8192
    float* bmin = e12 + 8192;                    // 2048 (512 used)
    float* bmax = bmin + 2048;                   // 2048 (512 used)
    float* lohi = bmax + 2048;                   // 2
    float* cntw = lohi + 2;                      // 16
    int*   off  = (int*)(ws + 2109504);          // 2B*257 = 65792 ints
    u16*   srcs = (u16*)(off + 65792);           // 2B*E u16 = 262144 float slots
    float* wts  = ws + 2437440;                  // 2B*E f32 = 524288 (ends 2961728)
    float* O1   = ws + 3223872;                  // 2*B*N*128 = 8388608
    float* O2   = O1 + 8388608;                  // 2*B*N*64  = 4194304

    float* O3Q = O3;
    float* O3C = O3 + (size_t)BB * NN * 32;
    float* e1w = e12;
    float* e2w = e12 + BB * 32;

    csr_kernel<<<2 * BB, 256, 0, stream>>>(eq, ec, off, srcs, wts);

    // L1: 4 chunks of 32 cols -> 1024 blocks (3/CU resident)
    gcn_fused6<128, 128, true, 1><<<4 * 2 * BB, 512, 0, stream>>>(
        xq, xc, W1, b1, off, srcs, wts, O1);
    // L2: 2 chunks -> 512 blocks
    gcn_fused6<128, 64, true, 1><<<2 * 2 * BB, 512, 0, stream>>>(
        O1, O1 + (size_t)BB * NN * 128, W2, b2, off, srcs, wts, O2);
    // L3: 1 chunk, NSPLIT=2 -> 512 blocks
    gcn_fused6<64, 32, false, 2><<<2 * 2 * BB, 512, 0, stream>>>(
        O2, O2 + (size_t)BB * NN * 64, W3, b3, off, srcs, wts, O3);

    attpool_kernel<<<2 * BB, 256, 0, stream>>>(O3, Watt, e12);

    pairdot_minmax<<<BB * 4, 256, 0, stream>>>(O3Q, O3C, bmin, bmax);
    minmax_kernel<<<1, 256, 0, stream>>>(bmin, bmax, lohi, cntw);
    pairdot_hist<<<BB * 4, 256, 0, stream>>>(O3Q, O3C, lohi, cntw);

    final_kernel<<<BB, 256, 0, stream>>>(e1w, e2w, ntnW, ntnV, ntnb, cntw,
                                         fc1W, fc1b, fc2W, fc2b, out);
}